// Round 14
// baseline (152.156 us; speedup 1.0000x reference)
//
#include <hip/hip_runtime.h>

using u16 = unsigned short;
using u32 = unsigned int;

typedef __bf16 bf16x8 __attribute__((ext_vector_type(8)));
typedef __bf16 bf16x4 __attribute__((ext_vector_type(4)));
typedef float f32x4 __attribute__((ext_vector_type(4)));
typedef u16 u16x4 __attribute__((ext_vector_type(4)));

#define GLD_LDS16(gp, lp)                                                                 \
  __builtin_amdgcn_global_load_lds((const __attribute__((address_space(1))) void*)(gp),   \
                                   (__attribute__((address_space(3))) void*)(lp), 16, 0, 0)

__device__ __forceinline__ u16 f2b(float f) {
  union { float f; u32 u; } v; v.f = f;
  return (u16)((v.u + 0x7fffu + ((v.u >> 16) & 1u)) >> 16);
}

// gfx950 half-swap cross-lane ops (VALU-rate). Operands must be DISTINCT
// SSA values (R5 lesson: same-value operands may coalesce into one VGPR).
__device__ __forceinline__ void pl32swap(u32& a, u32& b) {
  asm("v_permlane32_swap_b32 %0, %1" : "+v"(a), "+v"(b));
}
__device__ __forceinline__ void pl16swap(u32& a, u32& b) {
  asm("v_permlane16_swap_b32 %0, %1" : "+v"(a), "+v"(b));
}
__device__ __forceinline__ u32 cvtpk(float lo, float hi) {
  u32 d; asm("v_cvt_pk_bf16_f32 %0, %1, %2" : "=v"(d) : "v"(lo), "v"(hi));
  return d;
}
// single-instruction v_exp_f32 (R11 lesson: plain exp2f lowers to the
// multi-instruction __ocml_exp2_f32 libm call without fast-math)
#define EXP2(x) __builtin_amdgcn_exp2f(x)

// ---- prep: z<4 -> transpose+cast one 1024x1024 weight to bf16 W^T;
//      z=4/5 -> f32->bf16 of x / y; z=6 -> bias * log2e. One launch. ----
__global__ __launch_bounds__(256) void prep(
    const float* __restrict__ w0, const float* __restrict__ w1,
    const float* __restrict__ w2, const float* __restrict__ w3,
    u16* __restrict__ o0, u16* __restrict__ o1,
    u16* __restrict__ o2, u16* __restrict__ o3,
    const float* __restrict__ x, const float* __restrict__ y,
    u16* __restrict__ xb, u16* __restrict__ yb,
    const float* __restrict__ bias, float* __restrict__ bs) {
  __shared__ float tile[64][65];
  int z = blockIdx.z;
  if (z < 4) {
    const float* src; u16* dst;
    switch (z) {
      case 0: src = w0; dst = o0; break;
      case 1: src = w1; dst = o1; break;
      case 2: src = w2; dst = o2; break;
      default: src = w3; dst = o3; break;
    }
    int bx = blockIdx.x * 64, by = blockIdx.y * 64;
    int tx = threadIdx.x & 63, ty = threadIdx.x >> 6;
    for (int r = ty; r < 64; r += 4)
      tile[r][tx] = src[(size_t)(by + r) * 1024 + bx + tx];
    __syncthreads();
    for (int r = ty; r < 64; r += 4)
      dst[(size_t)(bx + r) * 1024 + by + tx] = f2b(tile[tx][r]);
  } else if (z < 6) {
    const float* src = (z == 4) ? x : y;
    u16* dst = (z == 4) ? xb : yb;
    size_t base = ((size_t)(blockIdx.y * 16 + blockIdx.x) * 256 + threadIdx.x) * 8;
    const size_t step = (size_t)256 * 256 * 8, total = (size_t)4096 * 1024;
    for (size_t i = base; i < total; i += step) {
      float4 f0 = *(const float4*)(src + i);
      float4 f1 = *(const float4*)(src + i + 4);
      bf16x8 v;
      v[0] = (__bf16)f0.x; v[1] = (__bf16)f0.y; v[2] = (__bf16)f0.z; v[3] = (__bf16)f0.w;
      v[4] = (__bf16)f1.x; v[5] = (__bf16)f1.y; v[6] = (__bf16)f1.z; v[7] = (__bf16)f1.w;
      *(bf16x8*)(dst + i) = v;
    }
  } else {
    if (blockIdx.x == 0 && blockIdx.y == 0)
      for (int i = threadIdx.x; i < 4096; i += 256)
        bs[i] = bias[i] * 1.44269504088896f;  // log2(e): exp->exp2 domain
  }
}

#define BM 128
#define BN 128
#define BK 64

// ------- fused QKV GEMM: region = blockIdx.y>>3 (0=Q,1=K,2=V); 768 blocks = 3/CU -------
// Q scale folds dh^-0.5 * log2(e) so flash softmax uses exp2 directly.
__global__ __launch_bounds__(256) void gemm_qkv(
    const u16* __restrict__ xb, const u16* __restrict__ yb, const u16* __restrict__ wT,
    u16* __restrict__ Qb, u16* __restrict__ Kb, u16* __restrict__ Vb) {
  __shared__ __align__(16) u16 As[BM * BK];
  __shared__ __align__(16) u16 Bs[BN * BK];
  const int K = 1024;
  int region = blockIdx.y >> 3;
  const u16* A = (region == 0) ? xb : yb;
  const u16* BT = wT + (size_t)region * 1024 * 1024;
  float scale = (region == 0) ? 0.125f * 1.44269504088896f : 1.0f;
  int tid = threadIdx.x;
  int wave = tid >> 6, lane = tid & 63;
  int r = lane & 15, kg = lane >> 4;
  int bm = blockIdx.x * BM, bn = (blockIdx.y & 7) * BN;
  int wr = (wave >> 1) * 64, wc = (wave & 1) * 64;
  f32x4 acc[4][4] = {};

  const u16* Ag = A + (size_t)(bm + wave * 32 + (lane >> 3)) * K + (lane & 7) * 8;
  const u16* Bg = BT + (size_t)(bn + wave * 32 + (lane >> 3)) * K + (lane & 7) * 8;
  u16* Asb = As + wave * 32 * BK;
  u16* Bsb = Bs + wave * 32 * BK;

  for (int k0 = 0; k0 < K; k0 += BK) {
#pragma unroll
    for (int c = 0; c < 4; ++c) {
      GLD_LDS16(Ag + (size_t)c * 8 * K + k0, Asb + c * 8 * BK);
      GLD_LDS16(Bg + (size_t)c * 8 * K + k0, Bsb + c * 8 * BK);
    }
    __syncthreads();
#pragma unroll
    for (int kk = 0; kk < 2; ++kk) {
      bf16x8 af[4], bfv[4];
#pragma unroll
      for (int m = 0; m < 4; ++m)
        af[m] = *(const bf16x8*)&As[(wr + m * 16 + r) * BK + kk * 32 + kg * 8];
#pragma unroll
      for (int n = 0; n < 4; ++n)
        bfv[n] = *(const bf16x8*)&Bs[(wc + n * 16 + r) * BK + kk * 32 + kg * 8];
#pragma unroll
      for (int m = 0; m < 4; ++m)
#pragma unroll
        for (int n = 0; n < 4; ++n)
          acc[m][n] = __builtin_amdgcn_mfma_f32_16x16x32_bf16(af[m], bfv[n], acc[m][n], 0, 0, 0);
    }
    __syncthreads();
  }

  if (region == 2) {
    // V^T per-head: [b][h][d][s], b=row>>11, s=row&2047, h=col>>6, d=col&63
#pragma unroll
    for (int m = 0; m < 4; ++m)
#pragma unroll
      for (int n = 0; n < 4; ++n) {
        int row0 = bm + wr + m * 16 + kg * 4;
        int col = bn + wc + n * 16 + r;
        int bb = row0 >> 11, s = row0 & 2047;
        int hh = col >> 6, dd = col & 63;
        u16x4 pk;
#pragma unroll
        for (int i = 0; i < 4; ++i) pk[i] = f2b(acc[m][n][i]);
        *(u16x4*)&Vb[((size_t)(bb * 16 + hh) * 64 + dd) * 2048 + s] = pk;
      }
  } else {
    u16* dst = (region == 0) ? Qb : Kb;
#pragma unroll
    for (int m = 0; m < 4; ++m)
#pragma unroll
      for (int n = 0; n < 4; ++n)
#pragma unroll
        for (int i = 0; i < 4; ++i) {
          int row = bm + wr + m * 16 + kg * 4 + i;
          int col = bn + wc + n * 16 + r;
          dst[(size_t)row * 1024 + col] = f2b(acc[m][n][i] * scale);
        }
  }
}

// ------- WO GEMM: C[4096][1024] f32 = A (bf16) * W.  BM=128, BN=64 -> 512 blocks (2/CU) -------
__global__ __launch_bounds__(256) void gemm_wo(
    const u16* __restrict__ A, const u16* __restrict__ BT, float* __restrict__ Cp,
    float scale) {
  __shared__ __align__(16) u16 As[BM * BK];
  __shared__ __align__(16) u16 Bs[64 * BK];
  const int K = 1024, N = 1024;
  int tid = threadIdx.x;
  int wave = tid >> 6, lane = tid & 63;
  int r = lane & 15, kg = lane >> 4;
  int lhi = lane >> 3, llo = lane & 7;
  int bm = blockIdx.x * BM, bn = blockIdx.y * 64;
  int wr = (wave >> 1) * 64, wc = (wave & 1) * 32;
  f32x4 acc[4][2] = {};

  const u16* Ag = A + (size_t)(bm + wave * 32 + lhi) * K + llo * 8;
  const u16* Bg = BT + (size_t)(bn + wave * 16 + lhi) * K + llo * 8;
  u16* Asb = As + wave * 32 * BK;
  u16* Bsb = Bs + wave * 16 * BK;

  for (int k0 = 0; k0 < K; k0 += BK) {
#pragma unroll
    for (int c = 0; c < 4; ++c)
      GLD_LDS16(Ag + (size_t)c * 8 * K + k0, Asb + c * 8 * BK);
#pragma unroll
    for (int c = 0; c < 2; ++c)
      GLD_LDS16(Bg + (size_t)c * 8 * K + k0, Bsb + c * 8 * BK);
    __syncthreads();
#pragma unroll
    for (int kk = 0; kk < 2; ++kk) {
      bf16x8 af[4], bfv[2];
#pragma unroll
      for (int m = 0; m < 4; ++m)
        af[m] = *(const bf16x8*)&As[(wr + m * 16 + r) * BK + kk * 32 + kg * 8];
#pragma unroll
      for (int n = 0; n < 2; ++n)
        bfv[n] = *(const bf16x8*)&Bs[(wc + n * 16 + r) * BK + kk * 32 + kg * 8];
#pragma unroll
      for (int m = 0; m < 4; ++m)
#pragma unroll
        for (int n = 0; n < 2; ++n)
          acc[m][n] = __builtin_amdgcn_mfma_f32_16x16x32_bf16(af[m], bfv[n], acc[m][n], 0, 0, 0);
    }
    __syncthreads();
  }

#pragma unroll
  for (int m = 0; m < 4; ++m)
#pragma unroll
    for (int n = 0; n < 2; ++n)
#pragma unroll
      for (int i = 0; i < 4; ++i) {
        int row = bm + wr + m * 16 + kg * 4 + i;
        int col = bn + wc + n * 16 + r;
        Cp[(size_t)row * N + col] = acc[m][n][i] * scale;
      }
}

// ---------------- flash attention: per (head, batch, 128-row qtile) ----------------
// R13 structure (8 waves, QBLK=128, T12 in-register P, exp2 softmax) with:
// (1) KVBLK=128 as two proven 64-key sub-tiles per barrier period (barriers
//     32 -> 17; all sub-tile index math identical to R13);
// (2) l-sum via MFMA ones-trick: acc_l = mfma(pa, ones, acc_l) gives
//     l[q] in the acc layout (replicated over cols) -- removes the 16-add
//     sum tree + 2 shfl_xor per sub-tile AND the epilogue __shfl.
__global__ __launch_bounds__(512) void flash_attn(
    const u16* __restrict__ Q, const u16* __restrict__ Km, const u16* __restrict__ VtG,
    const float* __restrict__ biasS, u16* __restrict__ ctx) {
  const int S = 2048, H = 1024;
  __shared__ __align__(16) u16 Ks[2][2][64 * 64];  // [buf][sub][key][d] (swizzled)
  __shared__ __align__(16) u16 Vs[2][2][64 * 64];  // [buf][sub][d][kv]  (swizzled)
  int tid = threadIdx.x;
  int wave = tid >> 6, lane = tid & 63;   // wave in [0,8)
  int r = lane & 15, kg = lane >> 4;
  int h = blockIdx.x, b = blockIdx.y, qt = blockIdx.z;

  const u16* Qb = Q + (size_t)(b * S + qt * 128 + wave * 16 + r) * H + h * 64 + kg * 8;
  bf16x8 qa[2];
  qa[0] = *(const bf16x8*)(Qb);
  qa[1] = *(const bf16x8*)(Qb + 32);

  bf16x8 onesv;
#pragma unroll
  for (int j = 0; j < 8; ++j) onesv[j] = (__bf16)1.0f;

  int lhi = lane >> 3, llo = lane & 7;
  int ksch = llo ^ lhi;  // pre-swizzled source chunk for DMA staging
  const u16* KgB = Km + (size_t)b * S * H + h * 64;
  const u16* VgB = VtG + ((size_t)(b * 16 + h) * 64) * 2048;  // rows d, stride S
  const float* biasB = biasS + (size_t)b * S;

  float m_i = -1e30f;
  f32x4 acc[4] = {};
  f32x4 acc_l = {};

  auto issueKV = [&](int kv0, int bi) {
    // wave w stages K keys [w*8, w*8+8) and V^T rows d in [w*8, w*8+8) per sub
#pragma unroll
    for (int sub = 0; sub < 2; ++sub) {
      GLD_LDS16(KgB + (size_t)(kv0 + sub * 64 + wave * 8 + lhi) * H + ksch * 8,
                &Ks[bi][sub][wave * 8 * 64]);
      GLD_LDS16(VgB + (size_t)(wave * 8 + lhi) * 2048 + kv0 + sub * 64 + ksch * 8,
                &Vs[bi][sub][wave * 8 * 64]);
    }
  };
  auto issueB = [&](int kv0, f32x4 (*bv)[4]) {
#pragma unroll
    for (int sub = 0; sub < 2; ++sub)
#pragma unroll
      for (int n = 0; n < 4; ++n)
        bv[sub][n] = *(const f32x4*)(biasB + kv0 + sub * 64 + n * 16 + (kg << 2));
  };

  auto computeSub = [&](const u16* KsB, const u16* VsB, const f32x4* bv) {
    // QK^T swapped: sv[n][i] = S^T[key = n*16+kg*4+i][q = r]
    f32x4 sv[4] = {};
    __builtin_amdgcn_s_setprio(1);
#pragma unroll
    for (int kk = 0; kk < 2; ++kk)
#pragma unroll
      for (int n = 0; n < 4; ++n) {
        bf16x8 kb = *(const bf16x8*)&KsB[(n * 16 + r) * 64 +
                                         ((((kk << 2) + kg) ^ (r & 7)) << 3)];
        sv[n] = __builtin_amdgcn_mfma_f32_16x16x32_bf16(kb, qa[kk], sv[n], 0, 0, 0);
      }
    __builtin_amdgcn_s_setprio(0);

    f32x4 s4[4];
#pragma unroll
    for (int n = 0; n < 4; ++n) s4[n] = sv[n] + bv[n];
    float m0 = fmaxf(fmaxf(s4[0][0], s4[0][1]), fmaxf(s4[0][2], s4[0][3]));
    float m1 = fmaxf(fmaxf(s4[1][0], s4[1][1]), fmaxf(s4[1][2], s4[1][3]));
    float m2 = fmaxf(fmaxf(s4[2][0], s4[2][1]), fmaxf(s4[2][2], s4[2][3]));
    float m3 = fmaxf(fmaxf(s4[3][0], s4[3][1]), fmaxf(s4[3][2], s4[3][3]));
    float mx = fmaxf(fmaxf(m0, m1), fmaxf(m2, m3));
    mx = fmaxf(mx, __shfl_xor(mx, 16));
    mx = fmaxf(mx, __shfl_xor(mx, 32));
    float sc = 1.f;
    if (mx > m_i + 8.f) { sc = EXP2(m_i - mx); m_i = mx; }
    if (__any(sc != 1.f)) {
#pragma unroll
      for (int i = 0; i < 4; ++i) {
        float sci = __shfl(sc, (lane & 48) | ((kg << 2) + i));
#pragma unroll
        for (int n = 0; n < 4; ++n) acc[n][i] *= sci;
        acc_l[i] *= sci;
      }
    }
    float e[4][4];
#pragma unroll
    for (int n = 0; n < 4; ++n)
#pragma unroll
      for (int i = 0; i < 4; ++i)
        e[n][i] = EXP2(s4[n][i] - m_i);

    // pack P: w[n][0] = keys n*16+kg*4+{0,1}, w[n][1] = +{2,3}
    u32 w[4][2];
#pragma unroll
    for (int n = 0; n < 4; ++n) {
      w[n][0] = cvtpk(e[n][0], e[n][1]);
      w[n][1] = cvtpk(e[n][2], e[n][3]);
    }

    // PV with in-register P redistribution; acc_l accumulates row-sum l[q]
    __builtin_amdgcn_s_setprio(1);
#pragma unroll
    for (int kk = 0; kk < 2; ++kk) {
      u32 a0 = w[2 * kk][0], a1 = w[2 * kk][1];
      u32 b0 = w[2 * kk + 1][0], b1 = w[2 * kk + 1][1];
      pl32swap(a0, b0); pl32swap(a1, b1);
      pl16swap(a0, b0); pl16swap(a1, b1);
      union { u32 u[4]; bf16x8 v; } pa;
      pa.u[0] = a0; pa.u[1] = a1; pa.u[2] = b0; pa.u[3] = b1;
#pragma unroll
      for (int n = 0; n < 4; ++n) {
        bf16x8 vb = *(const bf16x8*)&VsB[(n * 16 + r) * 64 +
                                         ((((kk << 2) + kg) ^ (r & 7)) << 3)];
        acc[n] = __builtin_amdgcn_mfma_f32_16x16x32_bf16(pa.v, vb, acc[n], 0, 0, 0);
      }
      acc_l = __builtin_amdgcn_mfma_f32_16x16x32_bf16(pa.v, onesv, acc_l, 0, 0, 0);
    }
    __builtin_amdgcn_s_setprio(0);
  };

  f32x4 bp[2][4], bn2[2][4];

  issueKV(0, 0); issueB(0, bp);
  __syncthreads();

  for (int t = 0; t < 16; ++t) {
    int bi = t & 1;
    int kvn = ((t + 1) & 15) * 128;  // wraps at end (harmless refetch)
    issueKV(kvn, bi ^ 1); issueB(kvn, bn2);
    computeSub(Ks[bi][0], Vs[bi][0], bp[0]);
    computeSub(Ks[bi][1], Vs[bi][1], bp[1]);
    __syncthreads();
#pragma unroll
    for (int sub = 0; sub < 2; ++sub)
#pragma unroll
      for (int n = 0; n < 4; ++n) bp[sub][n] = bn2[sub][n];
  }

#pragma unroll
  for (int i = 0; i < 4; ++i) {
    float inv = 1.0f / acc_l[i];
    size_t row = (size_t)(b * S + qt * 128 + wave * 16 + (kg << 2) + i);
#pragma unroll
    for (int n = 0; n < 4; ++n)
      ctx[row * H + h * 64 + n * 16 + r] = f2b(acc[n][i] * inv);
  }
}

extern "C" void kernel_launch(void* const* d_in, const int* in_sizes, int n_in,
                              void* d_out, int out_size, void* d_ws, size_t ws_size,
                              hipStream_t stream) {
  const float* x    = (const float*)d_in[0];
  const float* y    = (const float*)d_in[1];
  const float* bias = (const float*)d_in[2];
  const float* wq   = (const float*)d_in[3];
  const float* wk   = (const float*)d_in[4];
  const float* wv   = (const float*)d_in[5];
  const float* wo   = (const float*)d_in[6];
  float* out = (float*)d_out;  // reference output dtype is float32

  u16* ws = (u16*)d_ws;
  const size_t WELEM = 1024 * 1024;          // 2MB each (bf16)
  const size_t MELEM = (size_t)4096 * 1024;  // 8MB each (bf16)
  u16* wqT = ws;                 // wqT|wkT|wvT contiguous (gemm_qkv indexes by region)
  u16* wkT = wqT + WELEM;
  u16* wvT = wkT + WELEM;
  u16* woT = wvT + WELEM;
  u16* Qb  = woT + WELEM;
  u16* Kb  = Qb + MELEM;
  u16* Vb  = Kb + MELEM;   // holds V^T [b][h][d][s]
  u16* xb  = Vb + MELEM;   // x in bf16
  u16* yb  = xb + MELEM;   // y in bf16
  float* bs = (float*)(yb + MELEM);  // bias * log2e (f32, 4096)
  u16* Cb  = Qb;  // reuse: each flash block reads exactly the Q region it writes

  dim3 blk(256);
  prep<<<dim3(16, 16, 7), blk, 0, stream>>>(wq, wk, wv, wo, wqT, wkT, wvT, woT,
                                            x, y, xb, yb, bias, bs);
  gemm_qkv<<<dim3(32, 24), blk, 0, stream>>>(xb, yb, wqT, Qb, Kb, Vb);
  // (h,b) fastest -> same-(h,b) q-tiles share an XCD's L2
  flash_attn<<<dim3(16, 2, 16), dim3(512), 0, stream>>>(Qb, Kb, Vb, bs, Cb);
  gemm_wo<<<dim3(32, 16), blk, 0, stream>>>(Cb, woT, out, 1.0f);
}

// Round 15
// 137.897 us; speedup vs baseline: 1.1034x; 1.1034x over previous
//
#include <hip/hip_runtime.h>

using u16 = unsigned short;
using u32 = unsigned int;

typedef __bf16 bf16x8 __attribute__((ext_vector_type(8)));
typedef __bf16 bf16x4 __attribute__((ext_vector_type(4)));
typedef float f32x4 __attribute__((ext_vector_type(4)));
typedef u16 u16x4 __attribute__((ext_vector_type(4)));

#define GLD_LDS16(gp, lp)                                                                 \
  __builtin_amdgcn_global_load_lds((const __attribute__((address_space(1))) void*)(gp),   \
                                   (__attribute__((address_space(3))) void*)(lp), 16, 0, 0)

__device__ __forceinline__ u16 f2b(float f) {
  union { float f; u32 u; } v; v.f = f;
  return (u16)((v.u + 0x7fffu + ((v.u >> 16) & 1u)) >> 16);
}

// gfx950 half-swap cross-lane ops (VALU-rate). Operands must be DISTINCT
// SSA values (R5 lesson: same-value operands may coalesce into one VGPR).
__device__ __forceinline__ void pl32swap(u32& a, u32& b) {
  asm("v_permlane32_swap_b32 %0, %1" : "+v"(a), "+v"(b));
}
__device__ __forceinline__ void pl16swap(u32& a, u32& b) {
  asm("v_permlane16_swap_b32 %0, %1" : "+v"(a), "+v"(b));
}
__device__ __forceinline__ u32 cvtpk(float lo, float hi) {
  u32 d; asm("v_cvt_pk_bf16_f32 %0, %1, %2" : "=v"(d) : "v"(lo), "v"(hi));
  return d;
}
// single-instruction v_exp_f32 (R11 lesson: plain exp2f lowers to the
// multi-instruction __ocml_exp2_f32 libm call without fast-math)
#define EXP2(x) __builtin_amdgcn_exp2f(x)

// ---- prep: z<4 -> transpose+cast one 1024x1024 weight to bf16 W^T;
//      z=4/5 -> f32->bf16 of x / y; z=6 -> bias * log2e. One launch. ----
__global__ __launch_bounds__(256) void prep(
    const float* __restrict__ w0, const float* __restrict__ w1,
    const float* __restrict__ w2, const float* __restrict__ w3,
    u16* __restrict__ o0, u16* __restrict__ o1,
    u16* __restrict__ o2, u16* __restrict__ o3,
    const float* __restrict__ x, const float* __restrict__ y,
    u16* __restrict__ xb, u16* __restrict__ yb,
    const float* __restrict__ bias, float* __restrict__ bs) {
  __shared__ float tile[64][65];
  int z = blockIdx.z;
  if (z < 4) {
    const float* src; u16* dst;
    switch (z) {
      case 0: src = w0; dst = o0; break;
      case 1: src = w1; dst = o1; break;
      case 2: src = w2; dst = o2; break;
      default: src = w3; dst = o3; break;
    }
    int bx = blockIdx.x * 64, by = blockIdx.y * 64;
    int tx = threadIdx.x & 63, ty = threadIdx.x >> 6;
    for (int r = ty; r < 64; r += 4)
      tile[r][tx] = src[(size_t)(by + r) * 1024 + bx + tx];
    __syncthreads();
    for (int r = ty; r < 64; r += 4)
      dst[(size_t)(bx + r) * 1024 + by + tx] = f2b(tile[tx][r]);
  } else if (z < 6) {
    const float* src = (z == 4) ? x : y;
    u16* dst = (z == 4) ? xb : yb;
    size_t base = ((size_t)(blockIdx.y * 16 + blockIdx.x) * 256 + threadIdx.x) * 8;
    const size_t step = (size_t)256 * 256 * 8, total = (size_t)4096 * 1024;
    for (size_t i = base; i < total; i += step) {
      float4 f0 = *(const float4*)(src + i);
      float4 f1 = *(const float4*)(src + i + 4);
      bf16x8 v;
      v[0] = (__bf16)f0.x; v[1] = (__bf16)f0.y; v[2] = (__bf16)f0.z; v[3] = (__bf16)f0.w;
      v[4] = (__bf16)f1.x; v[5] = (__bf16)f1.y; v[6] = (__bf16)f1.z; v[7] = (__bf16)f1.w;
      *(bf16x8*)(dst + i) = v;
    }
  } else {
    if (blockIdx.x == 0 && blockIdx.y == 0)
      for (int i = threadIdx.x; i < 4096; i += 256)
        bs[i] = bias[i] * 1.44269504088896f;  // log2(e): exp->exp2 domain
  }
}

#define BM 128
#define BN 128
#define BK 64

// ------- fused QKV GEMM: region = blockIdx.y>>3 (0=Q,1=K,2=V); 768 blocks = 3/CU -------
// Q scale folds dh^-0.5 * log2(e) so flash softmax uses exp2 directly.
__global__ __launch_bounds__(256) void gemm_qkv(
    const u16* __restrict__ xb, const u16* __restrict__ yb, const u16* __restrict__ wT,
    u16* __restrict__ Qb, u16* __restrict__ Kb, u16* __restrict__ Vb) {
  __shared__ __align__(16) u16 As[BM * BK];
  __shared__ __align__(16) u16 Bs[BN * BK];
  const int K = 1024;
  int region = blockIdx.y >> 3;
  const u16* A = (region == 0) ? xb : yb;
  const u16* BT = wT + (size_t)region * 1024 * 1024;
  float scale = (region == 0) ? 0.125f * 1.44269504088896f : 1.0f;
  int tid = threadIdx.x;
  int wave = tid >> 6, lane = tid & 63;
  int r = lane & 15, kg = lane >> 4;
  int bm = blockIdx.x * BM, bn = (blockIdx.y & 7) * BN;
  int wr = (wave >> 1) * 64, wc = (wave & 1) * 64;
  f32x4 acc[4][4] = {};

  const u16* Ag = A + (size_t)(bm + wave * 32 + (lane >> 3)) * K + (lane & 7) * 8;
  const u16* Bg = BT + (size_t)(bn + wave * 32 + (lane >> 3)) * K + (lane & 7) * 8;
  u16* Asb = As + wave * 32 * BK;
  u16* Bsb = Bs + wave * 32 * BK;

  for (int k0 = 0; k0 < K; k0 += BK) {
#pragma unroll
    for (int c = 0; c < 4; ++c) {
      GLD_LDS16(Ag + (size_t)c * 8 * K + k0, Asb + c * 8 * BK);
      GLD_LDS16(Bg + (size_t)c * 8 * K + k0, Bsb + c * 8 * BK);
    }
    __syncthreads();
#pragma unroll
    for (int kk = 0; kk < 2; ++kk) {
      bf16x8 af[4], bfv[4];
#pragma unroll
      for (int m = 0; m < 4; ++m)
        af[m] = *(const bf16x8*)&As[(wr + m * 16 + r) * BK + kk * 32 + kg * 8];
#pragma unroll
      for (int n = 0; n < 4; ++n)
        bfv[n] = *(const bf16x8*)&Bs[(wc + n * 16 + r) * BK + kk * 32 + kg * 8];
#pragma unroll
      for (int m = 0; m < 4; ++m)
#pragma unroll
        for (int n = 0; n < 4; ++n)
          acc[m][n] = __builtin_amdgcn_mfma_f32_16x16x32_bf16(af[m], bfv[n], acc[m][n], 0, 0, 0);
    }
    __syncthreads();
  }

  if (region == 2) {
    // V^T per-head: [b][h][d][s], b=row>>11, s=row&2047, h=col>>6, d=col&63
#pragma unroll
    for (int m = 0; m < 4; ++m)
#pragma unroll
      for (int n = 0; n < 4; ++n) {
        int row0 = bm + wr + m * 16 + kg * 4;
        int col = bn + wc + n * 16 + r;
        int bb = row0 >> 11, s = row0 & 2047;
        int hh = col >> 6, dd = col & 63;
        u16x4 pk;
#pragma unroll
        for (int i = 0; i < 4; ++i) pk[i] = f2b(acc[m][n][i]);
        *(u16x4*)&Vb[((size_t)(bb * 16 + hh) * 64 + dd) * 2048 + s] = pk;
      }
  } else {
    u16* dst = (region == 0) ? Qb : Kb;
#pragma unroll
    for (int m = 0; m < 4; ++m)
#pragma unroll
      for (int n = 0; n < 4; ++n)
#pragma unroll
        for (int i = 0; i < 4; ++i) {
          int row = bm + wr + m * 16 + kg * 4 + i;
          int col = bn + wc + n * 16 + r;
          dst[(size_t)row * 1024 + col] = f2b(acc[m][n][i] * scale);
        }
  }
}

// ------- WO GEMM: C[4096][1024] f32 = A (bf16) * W.  BM=128, BN=64 -> 512 blocks (2/CU) -------
__global__ __launch_bounds__(256) void gemm_wo(
    const u16* __restrict__ A, const u16* __restrict__ BT, float* __restrict__ Cp,
    float scale) {
  __shared__ __align__(16) u16 As[BM * BK];
  __shared__ __align__(16) u16 Bs[64 * BK];
  const int K = 1024, N = 1024;
  int tid = threadIdx.x;
  int wave = tid >> 6, lane = tid & 63;
  int r = lane & 15, kg = lane >> 4;
  int lhi = lane >> 3, llo = lane & 7;
  int bm = blockIdx.x * BM, bn = blockIdx.y * 64;
  int wr = (wave >> 1) * 64, wc = (wave & 1) * 32;
  f32x4 acc[4][2] = {};

  const u16* Ag = A + (size_t)(bm + wave * 32 + lhi) * K + llo * 8;
  const u16* Bg = BT + (size_t)(bn + wave * 16 + lhi) * K + llo * 8;
  u16* Asb = As + wave * 32 * BK;
  u16* Bsb = Bs + wave * 16 * BK;

  for (int k0 = 0; k0 < K; k0 += BK) {
#pragma unroll
    for (int c = 0; c < 4; ++c)
      GLD_LDS16(Ag + (size_t)c * 8 * K + k0, Asb + c * 8 * BK);
#pragma unroll
    for (int c = 0; c < 2; ++c)
      GLD_LDS16(Bg + (size_t)c * 8 * K + k0, Bsb + c * 8 * BK);
    __syncthreads();
#pragma unroll
    for (int kk = 0; kk < 2; ++kk) {
      bf16x8 af[4], bfv[2];
#pragma unroll
      for (int m = 0; m < 4; ++m)
        af[m] = *(const bf16x8*)&As[(wr + m * 16 + r) * BK + kk * 32 + kg * 8];
#pragma unroll
      for (int n = 0; n < 2; ++n)
        bfv[n] = *(const bf16x8*)&Bs[(wc + n * 16 + r) * BK + kk * 32 + kg * 8];
#pragma unroll
      for (int m = 0; m < 4; ++m)
#pragma unroll
        for (int n = 0; n < 2; ++n)
          acc[m][n] = __builtin_amdgcn_mfma_f32_16x16x32_bf16(af[m], bfv[n], acc[m][n], 0, 0, 0);
    }
    __syncthreads();
  }

#pragma unroll
  for (int m = 0; m < 4; ++m)
#pragma unroll
    for (int n = 0; n < 2; ++n)
#pragma unroll
      for (int i = 0; i < 4; ++i) {
        int row = bm + wr + m * 16 + kg * 4 + i;
        int col = bn + wc + n * 16 + r;
        Cp[(size_t)row * N + col] = acc[m][n][i] * scale;
      }
}

// ---------------- flash attention: per (head, batch, 128-row qtile) ----------------
// R13-proven structure (8 waves / 512 threads, KVBLK=64, 32KB LDS, T12
// in-register P, exp2 softmax) + ONE change: l accumulated via the MFMA
// ones-trick (acc_l = mfma(pa, ones, acc_l) -> l[q] in acc layout) —
// deletes the 16-add sum tree, 2 shfl_xor, and the epilogue __shfl.
// Correctness of the trick proven in R14 (passed, absmax unchanged).
__global__ __launch_bounds__(512) void flash_attn(
    const u16* __restrict__ Q, const u16* __restrict__ Km, const u16* __restrict__ VtG,
    const float* __restrict__ biasS, u16* __restrict__ ctx) {
  const int S = 2048, H = 1024;
  __shared__ __align__(16) u16 Ks[2][64 * 64];   // [buf][key][d] (swizzled)
  __shared__ __align__(16) u16 Vs[2][64 * 64];   // [buf][d][kv]  (swizzled)
  int tid = threadIdx.x;
  int wave = tid >> 6, lane = tid & 63;   // wave in [0,8)
  int r = lane & 15, kg = lane >> 4;
  int h = blockIdx.x, b = blockIdx.y, qt = blockIdx.z;

  const u16* Qb = Q + (size_t)(b * S + qt * 128 + wave * 16 + r) * H + h * 64 + kg * 8;
  bf16x8 qa[2];
  qa[0] = *(const bf16x8*)(Qb);
  qa[1] = *(const bf16x8*)(Qb + 32);

  bf16x8 onesv;
#pragma unroll
  for (int j = 0; j < 8; ++j) onesv[j] = (__bf16)1.0f;

  int lhi = lane >> 3, llo = lane & 7;
  int ksch = llo ^ lhi;  // pre-swizzled source chunk for DMA staging
  const u16* KgB = Km + (size_t)b * S * H + h * 64;
  const u16* VgB = VtG + ((size_t)(b * 16 + h) * 64) * 2048;  // rows d, stride S
  const float* biasB = biasS + (size_t)b * S;

  float m_i = -1e30f;
  f32x4 acc[4] = {};
  f32x4 acc_l = {};

  auto issueKV = [&](int kv0, int bi) {
    // wave w stages K keys [w*8, w*8+8) and V^T rows d in [w*8, w*8+8)
    GLD_LDS16(KgB + (size_t)(kv0 + wave * 8 + lhi) * H + ksch * 8,
              &Ks[bi][wave * 8 * 64]);
    GLD_LDS16(VgB + (size_t)(wave * 8 + lhi) * 2048 + kv0 + ksch * 8,
              &Vs[bi][wave * 8 * 64]);
  };
  auto issueB = [&](int kv0, f32x4* bv) {
#pragma unroll
    for (int n = 0; n < 4; ++n)
      bv[n] = *(const f32x4*)(biasB + kv0 + n * 16 + (kg << 2));
  };

  auto compute = [&](const u16* KsB, const u16* VsB, const f32x4* bv) {
    // QK^T swapped: sv[n][i] = S^T[key = n*16+kg*4+i][q = r]
    f32x4 sv[4] = {};
    __builtin_amdgcn_s_setprio(1);
#pragma unroll
    for (int kk = 0; kk < 2; ++kk)
#pragma unroll
      for (int n = 0; n < 4; ++n) {
        bf16x8 kb = *(const bf16x8*)&KsB[(n * 16 + r) * 64 +
                                         ((((kk << 2) + kg) ^ (r & 7)) << 3)];
        sv[n] = __builtin_amdgcn_mfma_f32_16x16x32_bf16(kb, qa[kk], sv[n], 0, 0, 0);
      }
    __builtin_amdgcn_s_setprio(0);

    f32x4 s4[4];
#pragma unroll
    for (int n = 0; n < 4; ++n) s4[n] = sv[n] + bv[n];
    float m0 = fmaxf(fmaxf(s4[0][0], s4[0][1]), fmaxf(s4[0][2], s4[0][3]));
    float m1 = fmaxf(fmaxf(s4[1][0], s4[1][1]), fmaxf(s4[1][2], s4[1][3]));
    float m2 = fmaxf(fmaxf(s4[2][0], s4[2][1]), fmaxf(s4[2][2], s4[2][3]));
    float m3 = fmaxf(fmaxf(s4[3][0], s4[3][1]), fmaxf(s4[3][2], s4[3][3]));
    float mx = fmaxf(fmaxf(m0, m1), fmaxf(m2, m3));
    mx = fmaxf(mx, __shfl_xor(mx, 16));
    mx = fmaxf(mx, __shfl_xor(mx, 32));
    float sc = 1.f;
    if (mx > m_i + 8.f) { sc = EXP2(m_i - mx); m_i = mx; }
    if (__any(sc != 1.f)) {
#pragma unroll
      for (int i = 0; i < 4; ++i) {
        float sci = __shfl(sc, (lane & 48) | ((kg << 2) + i));
#pragma unroll
        for (int n = 0; n < 4; ++n) acc[n][i] *= sci;
        acc_l[i] *= sci;
      }
    }
    float e[4][4];
#pragma unroll
    for (int n = 0; n < 4; ++n)
#pragma unroll
      for (int i = 0; i < 4; ++i)
        e[n][i] = EXP2(s4[n][i] - m_i);

    // pack P: w[n][0] = keys n*16+kg*4+{0,1}, w[n][1] = +{2,3}
    u32 w[4][2];
#pragma unroll
    for (int n = 0; n < 4; ++n) {
      w[n][0] = cvtpk(e[n][0], e[n][1]);
      w[n][1] = cvtpk(e[n][2], e[n][3]);
    }

    // PV with in-register P redistribution; acc_l accumulates row-sum l[q]
    __builtin_amdgcn_s_setprio(1);
#pragma unroll
    for (int kk = 0; kk < 2; ++kk) {
      u32 a0 = w[2 * kk][0], a1 = w[2 * kk][1];
      u32 b0 = w[2 * kk + 1][0], b1 = w[2 * kk + 1][1];
      pl32swap(a0, b0); pl32swap(a1, b1);
      pl16swap(a0, b0); pl16swap(a1, b1);
      union { u32 u[4]; bf16x8 v; } pa;
      pa.u[0] = a0; pa.u[1] = a1; pa.u[2] = b0; pa.u[3] = b1;
#pragma unroll
      for (int n = 0; n < 4; ++n) {
        bf16x8 vb = *(const bf16x8*)&VsB[(n * 16 + r) * 64 +
                                         ((((kk << 2) + kg) ^ (r & 7)) << 3)];
        acc[n] = __builtin_amdgcn_mfma_f32_16x16x32_bf16(pa.v, vb, acc[n], 0, 0, 0);
      }
      acc_l = __builtin_amdgcn_mfma_f32_16x16x32_bf16(pa.v, onesv, acc_l, 0, 0, 0);
    }
    __builtin_amdgcn_s_setprio(0);
  };

  f32x4 bp[4], bn2[4];

  issueKV(0, 0); issueB(0, bp);
  __syncthreads();

  for (int t2 = 0; t2 < 16; ++t2) {
    int kv1 = (t2 * 2 + 1) * 64;
    int kv2 = ((t2 * 2 + 2) & 31) * 64;  // wraps at end (harmless refetch)
    issueKV(kv1, 1); issueB(kv1, bn2);
    compute(Ks[0], Vs[0], bp);
    __syncthreads();
    issueKV(kv2, 0); issueB(kv2, bp);
    compute(Ks[1], Vs[1], bn2);
    __syncthreads();
  }

#pragma unroll
  for (int i = 0; i < 4; ++i) {
    float inv = 1.0f / acc_l[i];
    size_t row = (size_t)(b * S + qt * 128 + wave * 16 + (kg << 2) + i);
#pragma unroll
    for (int n = 0; n < 4; ++n)
      ctx[row * H + h * 64 + n * 16 + r] = f2b(acc[n][i] * inv);
  }
}

extern "C" void kernel_launch(void* const* d_in, const int* in_sizes, int n_in,
                              void* d_out, int out_size, void* d_ws, size_t ws_size,
                              hipStream_t stream) {
  const float* x    = (const float*)d_in[0];
  const float* y    = (const float*)d_in[1];
  const float* bias = (const float*)d_in[2];
  const float* wq   = (const float*)d_in[3];
  const float* wk   = (const float*)d_in[4];
  const float* wv   = (const float*)d_in[5];
  const float* wo   = (const float*)d_in[6];
  float* out = (float*)d_out;  // reference output dtype is float32

  u16* ws = (u16*)d_ws;
  const size_t WELEM = 1024 * 1024;          // 2MB each (bf16)
  const size_t MELEM = (size_t)4096 * 1024;  // 8MB each (bf16)
  u16* wqT = ws;                 // wqT|wkT|wvT contiguous (gemm_qkv indexes by region)
  u16* wkT = wqT + WELEM;
  u16* wvT = wkT + WELEM;
  u16* woT = wvT + WELEM;
  u16* Qb  = woT + WELEM;
  u16* Kb  = Qb + MELEM;
  u16* Vb  = Kb + MELEM;   // holds V^T [b][h][d][s]
  u16* xb  = Vb + MELEM;   // x in bf16
  u16* yb  = xb + MELEM;   // y in bf16
  float* bs = (float*)(yb + MELEM);  // bias * log2e (f32, 4096)
  u16* Cb  = Qb;  // reuse: each flash block reads exactly the Q region it writes

  dim3 blk(256);
  prep<<<dim3(16, 16, 7), blk, 0, stream>>>(wq, wk, wv, wo, wqT, wkT, wvT, woT,
                                            x, y, xb, yb, bias, bs);
  gemm_qkv<<<dim3(32, 24), blk, 0, stream>>>(xb, yb, wqT, Qb, Kb, Vb);
  // (h,b) fastest -> same-(h,b) q-tiles share an XCD's L2
  flash_attn<<<dim3(16, 2, 16), dim3(512), 0, stream>>>(Qb, Kb, Vb, bs, Cb);
  gemm_wo<<<dim3(32, 16), blk, 0, stream>>>(Cb, woT, out, 1.0f);
}

// Round 16
// 133.388 us; speedup vs baseline: 1.1407x; 1.0338x over previous
//
#include <hip/hip_runtime.h>

using u16 = unsigned short;
using u32 = unsigned int;

typedef __bf16 bf16x8 __attribute__((ext_vector_type(8)));
typedef __bf16 bf16x4 __attribute__((ext_vector_type(4)));
typedef float f32x4 __attribute__((ext_vector_type(4)));
typedef u16 u16x4 __attribute__((ext_vector_type(4)));

#define GLD_LDS16(gp, lp)                                                                 \
  __builtin_amdgcn_global_load_lds((const __attribute__((address_space(1))) void*)(gp),   \
                                   (__attribute__((address_space(3))) void*)(lp), 16, 0, 0)

__device__ __forceinline__ u16 f2b(float f) {
  union { float f; u32 u; } v; v.f = f;
  return (u16)((v.u + 0x7fffu + ((v.u >> 16) & 1u)) >> 16);
}

// gfx950 half-swap cross-lane ops (VALU-rate). Operands must be DISTINCT
// SSA values (R5 lesson: same-value operands may coalesce into one VGPR).
__device__ __forceinline__ void pl32swap(u32& a, u32& b) {
  asm("v_permlane32_swap_b32 %0, %1" : "+v"(a), "+v"(b));
}
__device__ __forceinline__ void pl16swap(u32& a, u32& b) {
  asm("v_permlane16_swap_b32 %0, %1" : "+v"(a), "+v"(b));
}
__device__ __forceinline__ u32 cvtpk(float lo, float hi) {
  u32 d; asm("v_cvt_pk_bf16_f32 %0, %1, %2" : "=v"(d) : "v"(lo), "v"(hi));
  return d;
}
// single-instruction v_exp_f32 (R11 lesson: plain exp2f lowers to the
// multi-instruction __ocml_exp2_f32 libm call without fast-math)
#define EXP2(x) __builtin_amdgcn_exp2f(x)

// ---- prep: z<4 -> transpose+cast one 1024x1024 weight to bf16 W^T;
//      z=4/5 -> f32->bf16 of x / y; z=6 -> bias * log2e. One launch. ----
__global__ __launch_bounds__(256) void prep(
    const float* __restrict__ w0, const float* __restrict__ w1,
    const float* __restrict__ w2, const float* __restrict__ w3,
    u16* __restrict__ o0, u16* __restrict__ o1,
    u16* __restrict__ o2, u16* __restrict__ o3,
    const float* __restrict__ x, const float* __restrict__ y,
    u16* __restrict__ xb, u16* __restrict__ yb,
    const float* __restrict__ bias, float* __restrict__ bs) {
  __shared__ float tile[64][65];
  int z = blockIdx.z;
  if (z < 4) {
    const float* src; u16* dst;
    switch (z) {
      case 0: src = w0; dst = o0; break;
      case 1: src = w1; dst = o1; break;
      case 2: src = w2; dst = o2; break;
      default: src = w3; dst = o3; break;
    }
    int bx = blockIdx.x * 64, by = blockIdx.y * 64;
    int tx = threadIdx.x & 63, ty = threadIdx.x >> 6;
    for (int r = ty; r < 64; r += 4)
      tile[r][tx] = src[(size_t)(by + r) * 1024 + bx + tx];
    __syncthreads();
    for (int r = ty; r < 64; r += 4)
      dst[(size_t)(bx + r) * 1024 + by + tx] = f2b(tile[tx][r]);
  } else if (z < 6) {
    const float* src = (z == 4) ? x : y;
    u16* dst = (z == 4) ? xb : yb;
    size_t base = ((size_t)(blockIdx.y * 16 + blockIdx.x) * 256 + threadIdx.x) * 8;
    const size_t step = (size_t)256 * 256 * 8, total = (size_t)4096 * 1024;
    for (size_t i = base; i < total; i += step) {
      float4 f0 = *(const float4*)(src + i);
      float4 f1 = *(const float4*)(src + i + 4);
      bf16x8 v;
      v[0] = (__bf16)f0.x; v[1] = (__bf16)f0.y; v[2] = (__bf16)f0.z; v[3] = (__bf16)f0.w;
      v[4] = (__bf16)f1.x; v[5] = (__bf16)f1.y; v[6] = (__bf16)f1.z; v[7] = (__bf16)f1.w;
      *(bf16x8*)(dst + i) = v;
    }
  } else {
    if (blockIdx.x == 0 && blockIdx.y == 0)
      for (int i = threadIdx.x; i < 4096; i += 256)
        bs[i] = bias[i] * 1.44269504088896f;  // log2(e): exp->exp2 domain
  }
}

#define BM 128
#define BK 64

// ------- fused QKV GEMM, BN=64: region = blockIdx.y>>4 (0=Q,1=K,2=V).
// grid (32,48) = 1536 blocks; LDS 24KB -> ~6 blocks/CU (vs 3 at BN=128):
// wave-overlap hides the stage/barrier drain (R7 gemm_wo evidence).
// A-panel reuse stays XCD-local: id%8 = blockIdx.x%8 for all bn-blocks.
// Q scale folds dh^-0.5 * log2(e) so flash softmax uses exp2 directly.
__global__ __launch_bounds__(256) void gemm_qkv(
    const u16* __restrict__ xb, const u16* __restrict__ yb, const u16* __restrict__ wT,
    u16* __restrict__ Qb, u16* __restrict__ Kb, u16* __restrict__ Vb) {
  __shared__ __align__(16) u16 As[BM * BK];
  __shared__ __align__(16) u16 Bs[64 * BK];
  const int K = 1024;
  int region = blockIdx.y >> 4;
  const u16* A = (region == 0) ? xb : yb;
  const u16* BT = wT + (size_t)region * 1024 * 1024;
  float scale = (region == 0) ? 0.125f * 1.44269504088896f : 1.0f;
  int tid = threadIdx.x;
  int wave = tid >> 6, lane = tid & 63;
  int r = lane & 15, kg = lane >> 4;
  int lhi = lane >> 3, llo = lane & 7;
  int bm = blockIdx.x * BM, bn = (blockIdx.y & 15) * 64;
  int wr = (wave >> 1) * 64, wc = (wave & 1) * 32;
  f32x4 acc[4][2] = {};

  const u16* Ag = A + (size_t)(bm + wave * 32 + lhi) * K + llo * 8;
  const u16* Bg = BT + (size_t)(bn + wave * 16 + lhi) * K + llo * 8;
  u16* Asb = As + wave * 32 * BK;
  u16* Bsb = Bs + wave * 16 * BK;

  for (int k0 = 0; k0 < K; k0 += BK) {
#pragma unroll
    for (int c = 0; c < 4; ++c)
      GLD_LDS16(Ag + (size_t)c * 8 * K + k0, Asb + c * 8 * BK);
#pragma unroll
    for (int c = 0; c < 2; ++c)
      GLD_LDS16(Bg + (size_t)c * 8 * K + k0, Bsb + c * 8 * BK);
    __syncthreads();
#pragma unroll
    for (int kk = 0; kk < 2; ++kk) {
      bf16x8 af[4], bfv[2];
#pragma unroll
      for (int m = 0; m < 4; ++m)
        af[m] = *(const bf16x8*)&As[(wr + m * 16 + r) * BK + kk * 32 + kg * 8];
#pragma unroll
      for (int n = 0; n < 2; ++n)
        bfv[n] = *(const bf16x8*)&Bs[(wc + n * 16 + r) * BK + kk * 32 + kg * 8];
#pragma unroll
      for (int m = 0; m < 4; ++m)
#pragma unroll
        for (int n = 0; n < 2; ++n)
          acc[m][n] = __builtin_amdgcn_mfma_f32_16x16x32_bf16(af[m], bfv[n], acc[m][n], 0, 0, 0);
    }
    __syncthreads();
  }

  if (region == 2) {
    // V^T per-head: [b][h][d][s], b=row>>11, s=row&2047, h=col>>6, d=col&63
#pragma unroll
    for (int m = 0; m < 4; ++m)
#pragma unroll
      for (int n = 0; n < 2; ++n) {
        int row0 = bm + wr + m * 16 + kg * 4;
        int col = bn + wc + n * 16 + r;
        int bb = row0 >> 11, s = row0 & 2047;
        int hh = col >> 6, dd = col & 63;
        u16x4 pk;
#pragma unroll
        for (int i = 0; i < 4; ++i) pk[i] = f2b(acc[m][n][i]);
        *(u16x4*)&Vb[((size_t)(bb * 16 + hh) * 64 + dd) * 2048 + s] = pk;
      }
  } else {
    u16* dst = (region == 0) ? Qb : Kb;
#pragma unroll
    for (int m = 0; m < 4; ++m)
#pragma unroll
      for (int n = 0; n < 2; ++n)
#pragma unroll
        for (int i = 0; i < 4; ++i) {
          int row = bm + wr + m * 16 + kg * 4 + i;
          int col = bn + wc + n * 16 + r;
          dst[(size_t)row * 1024 + col] = f2b(acc[m][n][i] * scale);
        }
  }
}

// ------- WO GEMM: C[4096][1024] f32 = A (bf16) * W.  BM=128, BN=64 -> 512 blocks (2/CU) -------
__global__ __launch_bounds__(256) void gemm_wo(
    const u16* __restrict__ A, const u16* __restrict__ BT, float* __restrict__ Cp,
    float scale) {
  __shared__ __align__(16) u16 As[BM * BK];
  __shared__ __align__(16) u16 Bs[64 * BK];
  const int K = 1024, N = 1024;
  int tid = threadIdx.x;
  int wave = tid >> 6, lane = tid & 63;
  int r = lane & 15, kg = lane >> 4;
  int lhi = lane >> 3, llo = lane & 7;
  int bm = blockIdx.x * BM, bn = blockIdx.y * 64;
  int wr = (wave >> 1) * 64, wc = (wave & 1) * 32;
  f32x4 acc[4][2] = {};

  const u16* Ag = A + (size_t)(bm + wave * 32 + lhi) * K + llo * 8;
  const u16* Bg = BT + (size_t)(bn + wave * 16 + lhi) * K + llo * 8;
  u16* Asb = As + wave * 32 * BK;
  u16* Bsb = Bs + wave * 16 * BK;

  for (int k0 = 0; k0 < K; k0 += BK) {
#pragma unroll
    for (int c = 0; c < 4; ++c)
      GLD_LDS16(Ag + (size_t)c * 8 * K + k0, Asb + c * 8 * BK);
#pragma unroll
    for (int c = 0; c < 2; ++c)
      GLD_LDS16(Bg + (size_t)c * 8 * K + k0, Bsb + c * 8 * BK);
    __syncthreads();
#pragma unroll
    for (int kk = 0; kk < 2; ++kk) {
      bf16x8 af[4], bfv[2];
#pragma unroll
      for (int m = 0; m < 4; ++m)
        af[m] = *(const bf16x8*)&As[(wr + m * 16 + r) * BK + kk * 32 + kg * 8];
#pragma unroll
      for (int n = 0; n < 2; ++n)
        bfv[n] = *(const bf16x8*)&Bs[(wc + n * 16 + r) * BK + kk * 32 + kg * 8];
#pragma unroll
      for (int m = 0; m < 4; ++m)
#pragma unroll
        for (int n = 0; n < 2; ++n)
          acc[m][n] = __builtin_amdgcn_mfma_f32_16x16x32_bf16(af[m], bfv[n], acc[m][n], 0, 0, 0);
    }
    __syncthreads();
  }

#pragma unroll
  for (int m = 0; m < 4; ++m)
#pragma unroll
    for (int n = 0; n < 2; ++n)
#pragma unroll
      for (int i = 0; i < 4; ++i) {
        int row = bm + wr + m * 16 + kg * 4 + i;
        int col = bn + wc + n * 16 + r;
        Cp[(size_t)row * N + col] = acc[m][n][i] * scale;
      }
}

// ---------------- flash attention: per (head, batch, 128-row qtile) ----------------
// R15-proven: 8 waves / 512 threads, KVBLK=64, 32KB LDS, T12 in-register P,
// exp2 softmax (v_exp_f32), l via MFMA ones-trick. Byte-identical to R15.
__global__ __launch_bounds__(512) void flash_attn(
    const u16* __restrict__ Q, const u16* __restrict__ Km, const u16* __restrict__ VtG,
    const float* __restrict__ biasS, u16* __restrict__ ctx) {
  const int S = 2048, H = 1024;
  __shared__ __align__(16) u16 Ks[2][64 * 64];   // [buf][key][d] (swizzled)
  __shared__ __align__(16) u16 Vs[2][64 * 64];   // [buf][d][kv]  (swizzled)
  int tid = threadIdx.x;
  int wave = tid >> 6, lane = tid & 63;   // wave in [0,8)
  int r = lane & 15, kg = lane >> 4;
  int h = blockIdx.x, b = blockIdx.y, qt = blockIdx.z;

  const u16* Qb = Q + (size_t)(b * S + qt * 128 + wave * 16 + r) * H + h * 64 + kg * 8;
  bf16x8 qa[2];
  qa[0] = *(const bf16x8*)(Qb);
  qa[1] = *(const bf16x8*)(Qb + 32);

  bf16x8 onesv;
#pragma unroll
  for (int j = 0; j < 8; ++j) onesv[j] = (__bf16)1.0f;

  int lhi = lane >> 3, llo = lane & 7;
  int ksch = llo ^ lhi;  // pre-swizzled source chunk for DMA staging
  const u16* KgB = Km + (size_t)b * S * H + h * 64;
  const u16* VgB = VtG + ((size_t)(b * 16 + h) * 64) * 2048;  // rows d, stride S
  const float* biasB = biasS + (size_t)b * S;

  float m_i = -1e30f;
  f32x4 acc[4] = {};
  f32x4 acc_l = {};

  auto issueKV = [&](int kv0, int bi) {
    // wave w stages K keys [w*8, w*8+8) and V^T rows d in [w*8, w*8+8)
    GLD_LDS16(KgB + (size_t)(kv0 + wave * 8 + lhi) * H + ksch * 8,
              &Ks[bi][wave * 8 * 64]);
    GLD_LDS16(VgB + (size_t)(wave * 8 + lhi) * 2048 + kv0 + ksch * 8,
              &Vs[bi][wave * 8 * 64]);
  };
  auto issueB = [&](int kv0, f32x4* bv) {
#pragma unroll
    for (int n = 0; n < 4; ++n)
      bv[n] = *(const f32x4*)(biasB + kv0 + n * 16 + (kg << 2));
  };

  auto compute = [&](const u16* KsB, const u16* VsB, const f32x4* bv) {
    // QK^T swapped: sv[n][i] = S^T[key = n*16+kg*4+i][q = r]
    f32x4 sv[4] = {};
    __builtin_amdgcn_s_setprio(1);
#pragma unroll
    for (int kk = 0; kk < 2; ++kk)
#pragma unroll
      for (int n = 0; n < 4; ++n) {
        bf16x8 kb = *(const bf16x8*)&KsB[(n * 16 + r) * 64 +
                                         ((((kk << 2) + kg) ^ (r & 7)) << 3)];
        sv[n] = __builtin_amdgcn_mfma_f32_16x16x32_bf16(kb, qa[kk], sv[n], 0, 0, 0);
      }
    __builtin_amdgcn_s_setprio(0);

    f32x4 s4[4];
#pragma unroll
    for (int n = 0; n < 4; ++n) s4[n] = sv[n] + bv[n];
    float m0 = fmaxf(fmaxf(s4[0][0], s4[0][1]), fmaxf(s4[0][2], s4[0][3]));
    float m1 = fmaxf(fmaxf(s4[1][0], s4[1][1]), fmaxf(s4[1][2], s4[1][3]));
    float m2 = fmaxf(fmaxf(s4[2][0], s4[2][1]), fmaxf(s4[2][2], s4[2][3]));
    float m3 = fmaxf(fmaxf(s4[3][0], s4[3][1]), fmaxf(s4[3][2], s4[3][3]));
    float mx = fmaxf(fmaxf(m0, m1), fmaxf(m2, m3));
    mx = fmaxf(mx, __shfl_xor(mx, 16));
    mx = fmaxf(mx, __shfl_xor(mx, 32));
    float sc = 1.f;
    if (mx > m_i + 8.f) { sc = EXP2(m_i - mx); m_i = mx; }
    if (__any(sc != 1.f)) {
#pragma unroll
      for (int i = 0; i < 4; ++i) {
        float sci = __shfl(sc, (lane & 48) | ((kg << 2) + i));
#pragma unroll
        for (int n = 0; n < 4; ++n) acc[n][i] *= sci;
        acc_l[i] *= sci;
      }
    }
    float e[4][4];
#pragma unroll
    for (int n = 0; n < 4; ++n)
#pragma unroll
      for (int i = 0; i < 4; ++i)
        e[n][i] = EXP2(s4[n][i] - m_i);

    // pack P: w[n][0] = keys n*16+kg*4+{0,1}, w[n][1] = +{2,3}
    u32 w[4][2];
#pragma unroll
    for (int n = 0; n < 4; ++n) {
      w[n][0] = cvtpk(e[n][0], e[n][1]);
      w[n][1] = cvtpk(e[n][2], e[n][3]);
    }

    // PV with in-register P redistribution; acc_l accumulates row-sum l[q]
    __builtin_amdgcn_s_setprio(1);
#pragma unroll
    for (int kk = 0; kk < 2; ++kk) {
      u32 a0 = w[2 * kk][0], a1 = w[2 * kk][1];
      u32 b0 = w[2 * kk + 1][0], b1 = w[2 * kk + 1][1];
      pl32swap(a0, b0); pl32swap(a1, b1);
      pl16swap(a0, b0); pl16swap(a1, b1);
      union { u32 u[4]; bf16x8 v; } pa;
      pa.u[0] = a0; pa.u[1] = a1; pa.u[2] = b0; pa.u[3] = b1;
#pragma unroll
      for (int n = 0; n < 4; ++n) {
        bf16x8 vb = *(const bf16x8*)&VsB[(n * 16 + r) * 64 +
                                         ((((kk << 2) + kg) ^ (r & 7)) << 3)];
        acc[n] = __builtin_amdgcn_mfma_f32_16x16x32_bf16(pa.v, vb, acc[n], 0, 0, 0);
      }
      acc_l = __builtin_amdgcn_mfma_f32_16x16x32_bf16(pa.v, onesv, acc_l, 0, 0, 0);
    }
    __builtin_amdgcn_s_setprio(0);
  };

  f32x4 bp[4], bn2[4];

  issueKV(0, 0); issueB(0, bp);
  __syncthreads();

  for (int t2 = 0; t2 < 16; ++t2) {
    int kv1 = (t2 * 2 + 1) * 64;
    int kv2 = ((t2 * 2 + 2) & 31) * 64;  // wraps at end (harmless refetch)
    issueKV(kv1, 1); issueB(kv1, bn2);
    compute(Ks[0], Vs[0], bp);
    __syncthreads();
    issueKV(kv2, 0); issueB(kv2, bp);
    compute(Ks[1], Vs[1], bn2);
    __syncthreads();
  }

#pragma unroll
  for (int i = 0; i < 4; ++i) {
    float inv = 1.0f / acc_l[i];
    size_t row = (size_t)(b * S + qt * 128 + wave * 16 + (kg << 2) + i);
#pragma unroll
    for (int n = 0; n < 4; ++n)
      ctx[row * H + h * 64 + n * 16 + r] = f2b(acc[n][i] * inv);
  }
}

extern "C" void kernel_launch(void* const* d_in, const int* in_sizes, int n_in,
                              void* d_out, int out_size, void* d_ws, size_t ws_size,
                              hipStream_t stream) {
  const float* x    = (const float*)d_in[0];
  const float* y    = (const float*)d_in[1];
  const float* bias = (const float*)d_in[2];
  const float* wq   = (const float*)d_in[3];
  const float* wk   = (const float*)d_in[4];
  const float* wv   = (const float*)d_in[5];
  const float* wo   = (const float*)d_in[6];
  float* out = (float*)d_out;  // reference output dtype is float32

  u16* ws = (u16*)d_ws;
  const size_t WELEM = 1024 * 1024;          // 2MB each (bf16)
  const size_t MELEM = (size_t)4096 * 1024;  // 8MB each (bf16)
  u16* wqT = ws;                 // wqT|wkT|wvT contiguous (gemm_qkv indexes by region)
  u16* wkT = wqT + WELEM;
  u16* wvT = wkT + WELEM;
  u16* woT = wvT + WELEM;
  u16* Qb  = woT + WELEM;
  u16* Kb  = Qb + MELEM;
  u16* Vb  = Kb + MELEM;   // holds V^T [b][h][d][s]
  u16* xb  = Vb + MELEM;   // x in bf16
  u16* yb  = xb + MELEM;   // y in bf16
  float* bs = (float*)(yb + MELEM);  // bias * log2e (f32, 4096)
  u16* Cb  = Qb;  // reuse: each flash block reads exactly the Q region it writes

  dim3 blk(256);
  prep<<<dim3(16, 16, 7), blk, 0, stream>>>(wq, wk, wv, wo, wqT, wkT, wvT, woT,
                                            x, y, xb, yb, bias, bs);
  gemm_qkv<<<dim3(32, 48), blk, 0, stream>>>(xb, yb, wqT, Qb, Kb, Vb);
  // (h,b) fastest -> same-(h,b) q-tiles share an XCD's L2
  flash_attn<<<dim3(16, 2, 16), dim3(512), 0, stream>>>(Qb, Kb, Vb, bs, Cb);
  gemm_wo<<<dim3(32, 16), blk, 0, stream>>>(Cb, woT, out, 1.0f);
}